// Round 1
// baseline (363.642 us; speedup 1.0000x reference)
//
#include <hip/hip_runtime.h>
#include <stdint.h>

#define B_ 8
#define N_ 8192
#define S_ 2048
#define C1_ 128
#define C2_ 256
#define IN_ 384
#define H1_ 256
#define H2_ 128
#define M_ (B_*N_)   // 65536 rows

typedef short bf16x8 __attribute__((ext_vector_type(8)));
typedef float f32x4 __attribute__((ext_vector_type(4)));

__device__ __forceinline__ float bf2f(unsigned short s){
  union { unsigned int u; float f; } x; x.u = ((unsigned int)s) << 16; return x.f;
}
__device__ __forceinline__ unsigned short f2bf(float f){
  union { float f; unsigned int u; } x; x.f = f;
  unsigned int u = x.u;
  unsigned int r = (u + 0x7FFFu + ((u >> 16) & 1u)) >> 16;
  return (unsigned short)r;
}

// ---------------- prep: convert weights to bf16, zero stats ----------------
__global__ __launch_bounds__(256) void prep_kernel(const float* W1, const float* W2,
                                                   unsigned short* w1b, unsigned short* w2b,
                                                   float* stats){
  int i = blockIdx.x * 256 + threadIdx.x;
  if (i < 256*384) w1b[i] = f2bf(W1[i]);
  if (i < 128*256) w2b[i] = f2bf(W2[i]);
  if (i < 1536)    stats[i] = 0.f;
}

// ---------------- transpose [B][R][L] f32 -> out[b*L + l][stride] bf16 at col_off+r --------
__global__ __launch_bounds__(256) void transpose_kernel(const float* in, unsigned short* out,
                                                        int rows_in, int cols_in,
                                                        int out_stride, int out_col_off){
  __shared__ float tile[32][33];
  int b  = blockIdx.z;
  int l0 = blockIdx.x * 32, r0 = blockIdx.y * 32;
  int tx = threadIdx.x & 31, ty = threadIdx.x >> 5;
  const float* src = in + (size_t)b * rows_in * cols_in;
  #pragma unroll
  for (int rr = ty; rr < 32; rr += 8)
    tile[rr][tx] = src[(size_t)(r0 + rr) * cols_in + l0 + tx];
  __syncthreads();
  unsigned short* dst = out + (size_t)b * cols_in * out_stride;
  #pragma unroll
  for (int rr = ty; rr < 32; rr += 8)
    dst[(size_t)(l0 + rr) * out_stride + out_col_off + r0 + tx] = f2bf(tile[tx][rr]);
}

// ---------------- KNN: 3 nearest neighbors over S=2048, 4 interleaved lists ----------------
__global__ __launch_bounds__(256) void knn_kernel(const float* xyz1, const float* xyz2,
                                                  int* idx, float* wgt){
  __shared__ float4 pts[S_];   // 32 KB
  int b = blockIdx.y;
  int n = blockIdx.x * 256 + threadIdx.x;
  const float* x2 = xyz2 + (size_t)b * 3 * S_;
  for (int i = threadIdx.x; i < S_; i += 256){
    float px = x2[i], py = x2[S_ + i], pz = x2[2*S_ + i];
    pts[i] = make_float4(px, py, pz, px*px + py*py + pz*pz);
  }
  __syncthreads();
  const float* x1 = xyz1 + (size_t)b * 3 * N_;
  float ax = x1[n], ay = x1[N_ + n], az = x1[2*N_ + n];
  float x1sq = ax*ax + ay*ay + az*az;

  float bd[4][3]; int bi[4][3];
  #pragma unroll
  for (int u = 0; u < 4; u++){ bd[u][0]=bd[u][1]=bd[u][2]=1e30f; bi[u][0]=bi[u][1]=bi[u][2]=0; }

  for (int s = 0; s < S_; s += 4){
    #pragma unroll
    for (int u = 0; u < 4; u++){
      float4 p = pts[s + u];
      float dot = ax*p.x + ay*p.y + az*p.z;
      float dd  = p.w - 2.f*dot;               // d - |x1|^2 (monotone; add x1sq at end)
      bool c0 = dd < bd[u][0], c1 = dd < bd[u][1], c2 = dd < bd[u][2];
      bd[u][2] = c1 ? bd[u][1] : (c2 ? dd : bd[u][2]); bi[u][2] = c1 ? bi[u][1] : (c2 ? (s+u) : bi[u][2]);
      bd[u][1] = c0 ? bd[u][0] : (c1 ? dd : bd[u][1]); bi[u][1] = c0 ? bi[u][0] : (c1 ? (s+u) : bi[u][1]);
      bd[u][0] = c0 ? dd : bd[u][0];                    bi[u][0] = c0 ? (s+u) : bi[u][0];
    }
  }
  float d0 = bd[0][0], d1 = bd[0][1], d2 = bd[0][2];
  int   i0 = bi[0][0], i1 = bi[0][1], i2 = bi[0][2];
  #pragma unroll
  for (int u = 1; u < 4; u++){
    #pragma unroll
    for (int j = 0; j < 3; j++){
      float dd = bd[u][j]; int ss = bi[u][j];
      bool c0 = dd < d0, c1 = dd < d1, c2 = dd < d2;
      d2 = c1 ? d1 : (c2 ? dd : d2); i2 = c1 ? i1 : (c2 ? ss : i2);
      d1 = c0 ? d0 : (c1 ? dd : d1); i1 = c0 ? i0 : (c1 ? ss : i1);
      d0 = c0 ? dd : d0;             i0 = c0 ? ss : i0;
    }
  }
  float r0 = 1.f/(d0 + x1sq + 1e-8f);
  float r1 = 1.f/(d1 + x1sq + 1e-8f);
  float r2 = 1.f/(d2 + x1sq + 1e-8f);
  float rs = 1.f/(r0 + r1 + r2);
  size_t g = (size_t)b * N_ + n;
  idx[g*3+0] = i0; idx[g*3+1] = i1; idx[g*3+2] = i2;
  wgt[g*3+0] = r0*rs; wgt[g*3+1] = r1*rs; wgt[g*3+2] = r2*rs;
}

// ---------------- gather + weighted interp into x[:,128:384] ----------------
__global__ __launch_bounds__(256) void interp_kernel(const int* idx, const float* wgt,
                                                     const unsigned short* p2t, unsigned short* x){
  int t = threadIdx.x;                 // channel 0..255
  int base = blockIdx.x * 16;
  for (int k = 0; k < 16; k++){
    int g = base + k;
    int b = g >> 13;
    const int*   ip = idx + (size_t)g * 3;
    const float* wp = wgt + (size_t)g * 3;
    const unsigned short* p = p2t + (size_t)b * S_ * C2_;
    float v = wp[0]*bf2f(p[(size_t)ip[0]*C2_ + t])
            + wp[1]*bf2f(p[(size_t)ip[1]*C2_ + t])
            + wp[2]*bf2f(p[(size_t)ip[2]*C2_ + t]);
    x[(size_t)g * IN_ + C1_ + t] = f2bf(v);
  }
}

// ---------------- BN-affine + relu on 8 packed bf16 (for GEMM2 A-staging) ----------------
__device__ __forceinline__ uint4 bn_relu8(uint4 v, const float* a, const float* c, int kb){
  union { uint4 v; unsigned short s[8]; } u; u.v = v;
  #pragma unroll
  for (int j = 0; j < 8; j++){
    float f = bf2f(u.s[j]);
    f = fmaf(a[kb + j], f, c[kb + j]);
    u.s[j] = f2bf(fmaxf(f, 0.f));
  }
  return u.v;
}

// ---------------- MFMA GEMM: C[m,n] = sum_k A[m,k]*W[n,k]; 128x128 tile, BK=32 ------------
// Epilogue: store bf16 C, accumulate per-column sum / sumsq (for BN stats) via atomics.
__global__ __launch_bounds__(256) void gemm_bt_kernel(const unsigned short* A, const unsigned short* W,
                                                      unsigned short* Cout, int K, int Ntot,
                                                      float* sumv, float* sqv,
                                                      const float* aff_a, const float* aff_c){
  __shared__ unsigned short smA[128*32];  // 8 KB
  __shared__ unsigned short smB[128*32];  // 8 KB
  const int t    = threadIdx.x;
  const int lane = t & 63, wave = t >> 6;
  const int wm   = wave >> 1, wn = wave & 1;
  const size_t m0 = (size_t)blockIdx.x * 128;
  const int    n0 = blockIdx.y * 128;
  const int rowA = t >> 2, ch = t & 3;
  const unsigned short* Ab = A + (m0 + rowA) * (size_t)K + ch*8;
  const unsigned short* Bb = W + (size_t)(n0 + rowA) * K + ch*8;

  const f32x4 fzero = {0.f, 0.f, 0.f, 0.f};
  f32x4 acc[4][4];
  #pragma unroll
  for (int i = 0; i < 4; i++)
    #pragma unroll
    for (int j = 0; j < 4; j++) acc[i][j] = fzero;

  for (int k0 = 0; k0 < K; k0 += 32){
    uint4 va0 = *(const uint4*)(Ab + k0);
    uint4 va1 = *(const uint4*)(Ab + (size_t)64*K + k0);
    uint4 vb0 = *(const uint4*)(Bb + k0);
    uint4 vb1 = *(const uint4*)(Bb + (size_t)64*K + k0);
    if (aff_a){
      int kb = k0 + ch*8;
      va0 = bn_relu8(va0, aff_a, aff_c, kb);
      va1 = bn_relu8(va1, aff_a, aff_c, kb);
    }
    __syncthreads();
    *(uint4*)(&smA[t*8])         = va0;
    *(uint4*)(&smA[(t+256)*8])   = va1;
    *(uint4*)(&smB[t*8])         = vb0;
    *(uint4*)(&smB[(t+256)*8])   = vb1;
    __syncthreads();
    bf16x8 af[4], bfr[4];
    #pragma unroll
    for (int i = 0; i < 4; i++)
      af[i]  = *(const bf16x8*)(&smA[(wm*64 + i*16 + (lane & 15))*32 + (lane >> 4)*8]);
    #pragma unroll
    for (int j = 0; j < 4; j++)
      bfr[j] = *(const bf16x8*)(&smB[(wn*64 + j*16 + (lane & 15))*32 + (lane >> 4)*8]);
    #pragma unroll
    for (int i = 0; i < 4; i++)
      #pragma unroll
      for (int j = 0; j < 4; j++)
        acc[i][j] = __builtin_amdgcn_mfma_f32_16x16x32_bf16(af[i], bfr[j], acc[i][j], 0, 0, 0);
  }

  const int ln = lane & 15, lq = lane >> 4;
  #pragma unroll
  for (int j = 0; j < 4; j++){
    int ncol = n0 + wn*64 + j*16 + ln;
    float s = 0.f, q = 0.f;
    #pragma unroll
    for (int i = 0; i < 4; i++){
      size_t mrow = m0 + wm*64 + i*16 + lq*4;
      #pragma unroll
      for (int r = 0; r < 4; r++){
        float v = acc[i][j][r];
        Cout[(mrow + r) * Ntot + ncol] = f2bf(v);
        s += v; q += v*v;
      }
    }
    s += __shfl_xor(s, 16); s += __shfl_xor(s, 32);
    q += __shfl_xor(q, 16); q += __shfl_xor(q, 32);
    if (lq == 0){
      atomicAdd(&sumv[ncol], s);
      atomicAdd(&sqv[ncol], q);
    }
  }
}

// ---------------- finalize BN: a = g*rsqrt(var+eps), c = be - mean*a ----------------
__global__ void finalize_kernel(const float* sum, const float* sq, const float* g, const float* be,
                                float* a_out, float* c_out, int C){
  int c = threadIdx.x;
  if (c < C){
    float mean = sum[c] * (1.f / M_);
    float var  = sq[c]  * (1.f / M_) - mean*mean;
    float a = g[c] * rsqrtf(var + 1e-5f);
    a_out[c] = a;
    c_out[c] = fmaf(-mean, a, be[c]);
  }
}

// ---------------- final: BN2-affine + relu + transpose to [B,128,N] fp32 ----------------
__global__ __launch_bounds__(256) void out_kernel(const unsigned short* y2, const float* a2,
                                                  const float* c2, float* out){
  __shared__ float lds[64][65];
  int t  = threadIdx.x;
  int b  = blockIdx.z;
  int n0 = blockIdx.y * 64;
  int c0 = blockIdx.x * 64;
  int cc = t & 63, tr = t >> 6;
  float a = a2[c0 + cc], cadd = c2[c0 + cc];
  #pragma unroll
  for (int ph = 0; ph < 16; ph++){
    int nr = tr + ph*4;
    unsigned short v = y2[((size_t)(b*N_ + n0 + nr)) * H2_ + c0 + cc];
    lds[nr][cc] = fmaxf(fmaf(a, bf2f(v), cadd), 0.f);
  }
  __syncthreads();
  #pragma unroll
  for (int ph = 0; ph < 16; ph++){
    int cr = tr + ph*4;
    out[((size_t)(b*H2_ + c0 + cr)) * N_ + n0 + cc] = lds[cc][cr];
  }
}

extern "C" void kernel_launch(void* const* d_in, const int* in_sizes, int n_in,
                              void* d_out, int out_size, void* d_ws, size_t ws_size,
                              hipStream_t stream){
  const float* xyz1 = (const float*)d_in[0];
  const float* xyz2 = (const float*)d_in[1];
  const float* p1   = (const float*)d_in[2];
  const float* p2   = (const float*)d_in[3];
  const float* W1   = (const float*)d_in[4];
  const float* g1   = (const float*)d_in[6];
  const float* be1  = (const float*)d_in[7];
  const float* W2   = (const float*)d_in[8];
  const float* g2   = (const float*)d_in[10];
  const float* be2  = (const float*)d_in[11];
  float* out = (float*)d_out;

  char* ws = (char*)d_ws;
  unsigned short* x    = (unsigned short*)(ws + 0);          // [65536][384] bf16   50.3 MB
  unsigned short* p2t  = (unsigned short*)(ws + 50331648);   // [8][2048][256] bf16  8.4 MB
  unsigned short* y1   = (unsigned short*)(ws + 58720256);   // [65536][256] bf16   33.6 MB
  unsigned short* y2   = (unsigned short*)(ws + 92274688);   // [65536][128] bf16   16.8 MB
  unsigned short* w1b  = (unsigned short*)(ws + 109051904);  // [256][384] bf16
  unsigned short* w2b  = (unsigned short*)(ws + 109248512);  // [128][256] bf16
  int*            idx  = (int*)(ws + 109314048);             // [65536][3] int
  float*          wgt  = (float*)(ws + 110100480);           // [65536][3] f32
  float*          stats= (float*)(ws + 110886912);           // 1536 floats
  float* sum1 = stats;        float* sq1 = stats + 256;
  float* sum2 = stats + 512;  float* sq2 = stats + 640;
  float* a1   = stats + 768;  float* c1  = stats + 1024;
  float* a2   = stats + 1280; float* c2  = stats + 1408;

  prep_kernel<<<384, 256, 0, stream>>>(W1, W2, w1b, w2b, stats);
  transpose_kernel<<<dim3(64, 8, 8),  256, 0, stream>>>(p2, p2t, 256, 2048, 256, 0);
  transpose_kernel<<<dim3(256, 4, 8), 256, 0, stream>>>(p1, x,   128, 8192, 384, 0);
  knn_kernel<<<dim3(32, 8), 256, 0, stream>>>(xyz1, xyz2, idx, wgt);
  interp_kernel<<<4096, 256, 0, stream>>>(idx, wgt, p2t, x);
  gemm_bt_kernel<<<dim3(512, 2), 256, 0, stream>>>(x,  w1b, y1, 384, 256, sum1, sq1, nullptr, nullptr);
  finalize_kernel<<<1, 256, 0, stream>>>(sum1, sq1, g1, be1, a1, c1, 256);
  gemm_bt_kernel<<<dim3(512, 1), 256, 0, stream>>>(y1, w2b, y2, 256, 128, sum2, sq2, a1, c1);
  finalize_kernel<<<1, 256, 0, stream>>>(sum2, sq2, g2, be2, a2, c2, 128);
  out_kernel<<<dim3(2, 128, 8), 256, 0, stream>>>(y2, a2, c2, out);
}

// Round 3
// 334.586 us; speedup vs baseline: 1.0868x; 1.0868x over previous
//
#include <hip/hip_runtime.h>
#include <stdint.h>

#define B_ 8
#define N_ 8192
#define S_ 2048
#define C1_ 128
#define C2_ 256
#define IN_ 384
#define H1_ 256
#define H2_ 128
#define M_ (B_*N_)   // 65536 rows

typedef short bf16x8 __attribute__((ext_vector_type(8)));
typedef float f32x4 __attribute__((ext_vector_type(4)));

__device__ __forceinline__ float bf2f(unsigned short s){
  union { unsigned int u; float f; } x; x.u = ((unsigned int)s) << 16; return x.f;
}
__device__ __forceinline__ unsigned short f2bf(float f){
  union { float f; unsigned int u; } x; x.f = f;
  unsigned int u = x.u;
  unsigned int r = (u + 0x7FFFu + ((u >> 16) & 1u)) >> 16;
  return (unsigned short)r;
}

// ---------------- prep: convert weights to bf16, zero stats ----------------
__global__ __launch_bounds__(256) void prep_kernel(const float* W1, const float* W2,
                                                   unsigned short* w1b, unsigned short* w2b,
                                                   float* stats){
  int i = blockIdx.x * 256 + threadIdx.x;
  if (i < 256*384) w1b[i] = f2bf(W1[i]);
  if (i < 128*256) w2b[i] = f2bf(W2[i]);
  if (i < 1536)    stats[i] = 0.f;
}

// ---------------- transpose [B][R][L] f32 -> out[b*L + l][stride] bf16 at col_off+r --------
__global__ __launch_bounds__(256) void transpose_kernel(const float* in, unsigned short* out,
                                                        int rows_in, int cols_in,
                                                        int out_stride, int out_col_off){
  __shared__ float tile[32][33];
  int b  = blockIdx.z;
  int l0 = blockIdx.x * 32, r0 = blockIdx.y * 32;
  int tx = threadIdx.x & 31, ty = threadIdx.x >> 5;
  const float* src = in + (size_t)b * rows_in * cols_in;
  #pragma unroll
  for (int rr = ty; rr < 32; rr += 8)
    tile[rr][tx] = src[(size_t)(r0 + rr) * cols_in + l0 + tx];
  __syncthreads();
  unsigned short* dst = out + (size_t)b * cols_in * out_stride;
  #pragma unroll
  for (int rr = ty; rr < 32; rr += 8)
    dst[(size_t)(l0 + rr) * out_stride + out_col_off + r0 + tx] = f2bf(tile[tx][rr]);
}

// ---------------- KNN: exact fp32 sorted-insert (med3 for dists, cndmask for idx) --------
#define PIECES_ 4
#define SP_ (S_ / PIECES_)   // 512

__device__ __forceinline__ void insert3(float& d0, float& d1, float& d2,
                                        int& i0, int& i1, int& i2,
                                        float x, int s){
  bool b0 = x < d0, b1 = x < d1, b2 = x < d2;
  i2 = b1 ? i1 : (b2 ? s : i2);        // index updates read pre-update state
  i1 = b0 ? i0 : (b1 ? s : i1);
  i0 = b0 ? s : i0;
  d2 = __builtin_amdgcn_fmed3f(d1, d2, x);   // uses old d1
  d1 = __builtin_amdgcn_fmed3f(d0, d1, x);   // uses old d0,d1
  d0 = fminf(d0, x);
}

// pass 1: per S-piece exact top-3 (distances + indices) to scratch
__global__ __launch_bounds__(256) void knn_kernel(const float* xyz1, const float* xyz2,
                                                  float* partd, int* parti){
  __shared__ float4 pts[SP_];   // 8 KB
  int b = blockIdx.y, piece = blockIdx.z;
  int n = blockIdx.x * 256 + threadIdx.x;
  int base = piece * SP_;
  const float* x2 = xyz2 + (size_t)b * 3 * S_;
  for (int i = threadIdx.x; i < SP_; i += 256){
    float px = x2[base + i], py = x2[S_ + base + i], pz = x2[2*S_ + base + i];
    pts[i] = make_float4(-2.f*px, -2.f*py, -2.f*pz, px*px + py*py + pz*pz);
  }
  __syncthreads();
  const float* x1 = xyz1 + (size_t)b * 3 * N_;
  float ax = x1[n], ay = x1[N_ + n], az = x1[2*N_ + n];
  float x1sq = ax*ax + ay*ay + az*az;

  float d[4][3]; int id[4][3];
  #pragma unroll
  for (int u = 0; u < 4; u++){
    d[u][0] = d[u][1] = d[u][2] = 1e30f;
    id[u][0] = id[u][1] = id[u][2] = 0;
  }

  float4 nxt0 = pts[0], nxt1 = pts[1], nxt2 = pts[2], nxt3 = pts[3];
  for (int s = 0; s < SP_; s += 4){
    float4 c0 = nxt0, c1 = nxt1, c2 = nxt2, c3 = nxt3;
    int sp = (s + 4) & (SP_ - 1);
    nxt0 = pts[sp]; nxt1 = pts[sp+1]; nxt2 = pts[sp+2]; nxt3 = pts[sp+3];
    #pragma unroll
    for (int u = 0; u < 4; u++){
      float4 c = (u==0)?c0 : (u==1)?c1 : (u==2)?c2 : c3;
      float dd = fmaf(ax, c.x, fmaf(ay, c.y, fmaf(az, c.z, c.w + x1sq)));
      insert3(d[u][0], d[u][1], d[u][2], id[u][0], id[u][1], id[u][2], dd, base + s + u);
    }
  }
  // merge 4 interleaved lists -> one sorted top-3 (exact)
  float e0 = d[0][0], e1 = d[0][1], e2 = d[0][2];
  int   j0 = id[0][0], j1 = id[0][1], j2 = id[0][2];
  #pragma unroll
  for (int u = 1; u < 4; u++)
    #pragma unroll
    for (int j = 0; j < 3; j++)
      insert3(e0, e1, e2, j0, j1, j2, d[u][j], id[u][j]);

  size_t g = (size_t)b * N_ + n;
  partd[(piece*3 + 0)*(size_t)M_ + g] = e0;
  partd[(piece*3 + 1)*(size_t)M_ + g] = e1;
  partd[(piece*3 + 2)*(size_t)M_ + g] = e2;
  parti[(piece*3 + 0)*(size_t)M_ + g] = j0;
  parti[(piece*3 + 1)*(size_t)M_ + g] = j1;
  parti[(piece*3 + 2)*(size_t)M_ + g] = j2;
}

// pass 2: merge 4 pieces' exact top-3, compute weights
__global__ __launch_bounds__(256) void knn_merge_kernel(const float* partd, const int* parti,
                                                        int* idx, float* wgt){
  size_t g = (size_t)blockIdx.x * 256 + threadIdx.x;
  float d0 = partd[0*(size_t)M_ + g], d1 = partd[1*(size_t)M_ + g], d2 = partd[2*(size_t)M_ + g];
  int   i0 = parti[0*(size_t)M_ + g], i1 = parti[1*(size_t)M_ + g], i2 = parti[2*(size_t)M_ + g];
  #pragma unroll
  for (int p = 1; p < PIECES_; p++)
    #pragma unroll
    for (int j = 0; j < 3; j++)
      insert3(d0, d1, d2, i0, i1, i2,
              partd[(p*3 + j)*(size_t)M_ + g], parti[(p*3 + j)*(size_t)M_ + g]);

  float e0 = fmaxf(d0, 0.f), e1 = fmaxf(d1, 0.f), e2 = fmaxf(d2, 0.f);
  float r0 = 1.f/(e0 + 1e-8f), r1 = 1.f/(e1 + 1e-8f), r2 = 1.f/(e2 + 1e-8f);
  float rs = 1.f/(r0 + r1 + r2);
  idx[g*3+0] = i0; idx[g*3+1] = i1; idx[g*3+2] = i2;
  wgt[g*3+0] = r0*rs; wgt[g*3+1] = r1*rs; wgt[g*3+2] = r2*rs;
}

// ---------------- gather + weighted interp into x[:,128:384] ----------------
__global__ __launch_bounds__(256) void interp_kernel(const int* idx, const float* wgt,
                                                     const unsigned short* p2t, unsigned short* x){
  int t = threadIdx.x;                 // channel 0..255
  int base = blockIdx.x * 16;
  for (int k = 0; k < 16; k++){
    int g = base + k;
    int b = g >> 13;
    const int*   ip = idx + (size_t)g * 3;
    const float* wp = wgt + (size_t)g * 3;
    const unsigned short* p = p2t + (size_t)b * S_ * C2_;
    float v = wp[0]*bf2f(p[(size_t)ip[0]*C2_ + t])
            + wp[1]*bf2f(p[(size_t)ip[1]*C2_ + t])
            + wp[2]*bf2f(p[(size_t)ip[2]*C2_ + t]);
    x[(size_t)g * IN_ + C1_ + t] = f2bf(v);
  }
}

// ---------------- BN-affine + relu on 8 packed bf16 (for GEMM2 A-staging) ----------------
__device__ __forceinline__ uint4 bn_relu8(uint4 v, const float* a, const float* c, int kb){
  union { uint4 v; unsigned short s[8]; } u; u.v = v;
  #pragma unroll
  for (int j = 0; j < 8; j++){
    float f = bf2f(u.s[j]);
    f = fmaf(a[kb + j], f, c[kb + j]);
    u.s[j] = f2bf(fmaxf(f, 0.f));
  }
  return u.v;
}

// ---------------- MFMA GEMM: C[m,n] = sum_k A[m,k]*W[n,k]; 128x128 tile, BK=32 ------------
__global__ __launch_bounds__(256) void gemm_bt_kernel(const unsigned short* A, const unsigned short* W,
                                                      unsigned short* Cout, int K, int Ntot,
                                                      float* sumv, float* sqv,
                                                      const float* aff_a, const float* aff_c){
  __shared__ unsigned short smA[128*32];  // 8 KB
  __shared__ unsigned short smB[128*32];  // 8 KB
  const int t    = threadIdx.x;
  const int lane = t & 63, wave = t >> 6;
  const int wm   = wave >> 1, wn = wave & 1;
  const size_t m0 = (size_t)blockIdx.x * 128;
  const int    n0 = blockIdx.y * 128;
  const int rowA = t >> 2, ch = t & 3;
  const unsigned short* Ab = A + (m0 + rowA) * (size_t)K + ch*8;
  const unsigned short* Bb = W + (size_t)(n0 + rowA) * K + ch*8;

  const f32x4 fzero = {0.f, 0.f, 0.f, 0.f};
  f32x4 acc[4][4];
  #pragma unroll
  for (int i = 0; i < 4; i++)
    #pragma unroll
    for (int j = 0; j < 4; j++) acc[i][j] = fzero;

  for (int k0 = 0; k0 < K; k0 += 32){
    uint4 va0 = *(const uint4*)(Ab + k0);
    uint4 va1 = *(const uint4*)(Ab + (size_t)64*K + k0);
    uint4 vb0 = *(const uint4*)(Bb + k0);
    uint4 vb1 = *(const uint4*)(Bb + (size_t)64*K + k0);
    if (aff_a){
      int kb = k0 + ch*8;
      va0 = bn_relu8(va0, aff_a, aff_c, kb);
      va1 = bn_relu8(va1, aff_a, aff_c, kb);
    }
    __syncthreads();
    *(uint4*)(&smA[t*8])         = va0;
    *(uint4*)(&smA[(t+256)*8])   = va1;
    *(uint4*)(&smB[t*8])         = vb0;
    *(uint4*)(&smB[(t+256)*8])   = vb1;
    __syncthreads();
    bf16x8 af[4], bfr[4];
    #pragma unroll
    for (int i = 0; i < 4; i++)
      af[i]  = *(const bf16x8*)(&smA[(wm*64 + i*16 + (lane & 15))*32 + (lane >> 4)*8]);
    #pragma unroll
    for (int j = 0; j < 4; j++)
      bfr[j] = *(const bf16x8*)(&smB[(wn*64 + j*16 + (lane & 15))*32 + (lane >> 4)*8]);
    #pragma unroll
    for (int i = 0; i < 4; i++)
      #pragma unroll
      for (int j = 0; j < 4; j++)
        acc[i][j] = __builtin_amdgcn_mfma_f32_16x16x32_bf16(af[i], bfr[j], acc[i][j], 0, 0, 0);
  }

  const int ln = lane & 15, lq = lane >> 4;
  #pragma unroll
  for (int j = 0; j < 4; j++){
    int ncol = n0 + wn*64 + j*16 + ln;
    float s = 0.f, q = 0.f;
    #pragma unroll
    for (int i = 0; i < 4; i++){
      size_t mrow = m0 + wm*64 + i*16 + lq*4;
      #pragma unroll
      for (int r = 0; r < 4; r++){
        float v = acc[i][j][r];
        Cout[(mrow + r) * Ntot + ncol] = f2bf(v);
        s += v; q += v*v;
      }
    }
    s += __shfl_xor(s, 16); s += __shfl_xor(s, 32);
    q += __shfl_xor(q, 16); q += __shfl_xor(q, 32);
    if (lq == 0){
      atomicAdd(&sumv[ncol], s);
      atomicAdd(&sqv[ncol], q);
    }
  }
}

// ---------------- finalize BN: a = g*rsqrt(var+eps), c = be - mean*a ----------------
__global__ void finalize_kernel(const float* sum, const float* sq, const float* g, const float* be,
                                float* a_out, float* c_out, int C){
  int c = threadIdx.x;
  if (c < C){
    float mean = sum[c] * (1.f / M_);
    float var  = sq[c]  * (1.f / M_) - mean*mean;
    float a = g[c] * rsqrtf(var + 1e-5f);
    a_out[c] = a;
    c_out[c] = fmaf(-mean, a, be[c]);
  }
}

// ---------------- final: BN2-affine + relu + transpose to [B,128,N] fp32 ----------------
__global__ __launch_bounds__(256) void out_kernel(const unsigned short* y2, const float* a2,
                                                  const float* c2, float* out){
  __shared__ float lds[64][65];
  int t  = threadIdx.x;
  int b  = blockIdx.z;
  int n0 = blockIdx.y * 64;
  int c0 = blockIdx.x * 64;
  int cc = t & 63, tr = t >> 6;
  float a = a2[c0 + cc], cadd = c2[c0 + cc];
  #pragma unroll
  for (int ph = 0; ph < 16; ph++){
    int nr = tr + ph*4;
    unsigned short v = y2[((size_t)(b*N_ + n0 + nr)) * H2_ + c0 + cc];
    lds[nr][cc] = fmaxf(fmaf(a, bf2f(v), cadd), 0.f);
  }
  __syncthreads();
  #pragma unroll
  for (int ph = 0; ph < 16; ph++){
    int cr = tr + ph*4;
    out[((size_t)(b*H2_ + c0 + cr)) * N_ + n0 + cc] = lds[cc][cr];
  }
}

extern "C" void kernel_launch(void* const* d_in, const int* in_sizes, int n_in,
                              void* d_out, int out_size, void* d_ws, size_t ws_size,
                              hipStream_t stream){
  const float* xyz1 = (const float*)d_in[0];
  const float* xyz2 = (const float*)d_in[1];
  const float* p1   = (const float*)d_in[2];
  const float* p2   = (const float*)d_in[3];
  const float* W1   = (const float*)d_in[4];
  const float* g1   = (const float*)d_in[6];
  const float* be1  = (const float*)d_in[7];
  const float* W2   = (const float*)d_in[8];
  const float* g2   = (const float*)d_in[10];
  const float* be2  = (const float*)d_in[11];
  float* out = (float*)d_out;

  char* ws = (char*)d_ws;
  unsigned short* x    = (unsigned short*)(ws + 0);          // [65536][384] bf16   50.3 MB
  unsigned short* p2t  = (unsigned short*)(ws + 50331648);   // [8][2048][256] bf16  8.4 MB
  unsigned short* y1   = (unsigned short*)(ws + 58720256);   // [65536][256] bf16   33.6 MB
  unsigned short* y2   = (unsigned short*)(ws + 92274688);   // [65536][128] bf16   16.8 MB
  unsigned short* w1b  = (unsigned short*)(ws + 109051904);  // [256][384] bf16
  unsigned short* w2b  = (unsigned short*)(ws + 109248512);  // [128][256] bf16
  int*            idx  = (int*)(ws + 109314048);             // [65536][3] int
  float*          wgt  = (float*)(ws + 110100480);           // [65536][3] f32
  float*          stats= (float*)(ws + 110886912);           // 1536 floats
  float* sum1 = stats;        float* sq1 = stats + 256;
  float* sum2 = stats + 512;  float* sq2 = stats + 640;
  float* a1   = stats + 768;  float* c1  = stats + 1024;
  float* a2   = stats + 1280; float* c2  = stats + 1408;
  // knn partials reuse y1 region (d: 3.1 MB + i: 3.1 MB; y1 written only later by gemm1)
  float* partd = (float*)y1;
  int*   parti = (int*)(y1 + 6291456);   // offset 12 MB into y1 region (elements are 2B)

  prep_kernel<<<384, 256, 0, stream>>>(W1, W2, w1b, w2b, stats);
  transpose_kernel<<<dim3(64, 8, 8),  256, 0, stream>>>(p2, p2t, 256, 2048, 256, 0);
  transpose_kernel<<<dim3(256, 4, 8), 256, 0, stream>>>(p1, x,   128, 8192, 384, 0);
  knn_kernel<<<dim3(32, 8, PIECES_), 256, 0, stream>>>(xyz1, xyz2, partd, parti);
  knn_merge_kernel<<<256, 256, 0, stream>>>(partd, parti, idx, wgt);
  interp_kernel<<<4096, 256, 0, stream>>>(idx, wgt, p2t, x);
  gemm_bt_kernel<<<dim3(512, 2), 256, 0, stream>>>(x,  w1b, y1, 384, 256, sum1, sq1, nullptr, nullptr);
  finalize_kernel<<<1, 256, 0, stream>>>(sum1, sq1, g1, be1, a1, c1, 256);
  gemm_bt_kernel<<<dim3(512, 1), 256, 0, stream>>>(y1, w2b, y2, 256, 128, sum2, sq2, a1, c1);
  finalize_kernel<<<1, 256, 0, stream>>>(sum2, sq2, g2, be2, a2, c2, 128);
  out_kernel<<<dim3(2, 128, 8), 256, 0, stream>>>(y2, a2, c2, out);
}

// Round 5
// 319.044 us; speedup vs baseline: 1.1398x; 1.0487x over previous
//
#include <hip/hip_runtime.h>
#include <stdint.h>

#define B_ 8
#define N_ 8192
#define S_ 2048
#define C1_ 128
#define C2_ 256
#define IN_ 384
#define H1_ 256
#define H2_ 128
#define M_ (B_*N_)   // 65536 rows

typedef short bf16x8 __attribute__((ext_vector_type(8)));
typedef float f32x4 __attribute__((ext_vector_type(4)));

__device__ __forceinline__ float bf2f(unsigned short s){
  union { unsigned int u; float f; } x; x.u = ((unsigned int)s) << 16; return x.f;
}
__device__ __forceinline__ unsigned short f2bf(float f){
  union { float f; unsigned int u; } x; x.f = f;
  unsigned int u = x.u;
  unsigned int r = (u + 0x7FFFu + ((u >> 16) & 1u)) >> 16;
  return (unsigned short)r;
}

// ---------------- prep: convert weights to bf16, zero stats ----------------
__global__ __launch_bounds__(256) void prep_kernel(const float* W1, const float* W2,
                                                   unsigned short* w1b, unsigned short* w2b,
                                                   float* stats){
  int i = blockIdx.x * 256 + threadIdx.x;
  if (i < 256*384) w1b[i] = f2bf(W1[i]);
  if (i < 128*256) w2b[i] = f2bf(W2[i]);
  if (i < 1536)    stats[i] = 0.f;
}

// ---------------- transpose [B][R][L] f32 -> out[b*L + l][stride] bf16 at col_off+r --------
__global__ __launch_bounds__(256) void transpose_kernel(const float* in, unsigned short* out,
                                                        int rows_in, int cols_in,
                                                        int out_stride, int out_col_off){
  __shared__ float tile[32][33];
  int b  = blockIdx.z;
  int l0 = blockIdx.x * 32, r0 = blockIdx.y * 32;
  int tx = threadIdx.x & 31, ty = threadIdx.x >> 5;
  const float* src = in + (size_t)b * rows_in * cols_in;
  #pragma unroll
  for (int rr = ty; rr < 32; rr += 8)
    tile[rr][tx] = src[(size_t)(r0 + rr) * cols_in + l0 + tx];
  __syncthreads();
  unsigned short* dst = out + (size_t)b * cols_in * out_stride;
  #pragma unroll
  for (int rr = ty; rr < 32; rr += 8)
    dst[(size_t)(l0 + rr) * out_stride + out_col_off + r0 + tx] = f2bf(tile[tx][rr]);
}

// ---------------- KNN: exact fp32 sorted-insert, LDS-staged candidates --------------------
#define PIECES_ 8
#define SPP_ (S_ / PIECES_)   // 256

__device__ __forceinline__ void insert3(float& d0, float& d1, float& d2,
                                        int& i0, int& i1, int& i2,
                                        float x, int s){
  bool b0 = x < d0, b1 = x < d1, b2 = x < d2;
  i2 = b1 ? i1 : (b2 ? s : i2);        // index updates read pre-update state
  i1 = b0 ? i0 : (b1 ? s : i1);
  i0 = b0 ? s : i0;
  d2 = __builtin_amdgcn_fmed3f(d1, d2, x);   // uses old d1
  d1 = __builtin_amdgcn_fmed3f(d0, d1, x);   // uses old d0,d1
  d0 = fminf(d0, x);
}

// pass 1: per S-piece exact top-3 in (d - |x1|^2) space
__global__ __launch_bounds__(256, 8) void knn_kernel(const float* xyz1, const float* xyz2,
                                                     float* partd, int* parti){
  __shared__ float4 pts[SPP_];   // 4 KB
  int b = blockIdx.y, piece = blockIdx.z;
  int n = blockIdx.x * 256 + threadIdx.x;
  int base = piece * SPP_;
  const float* x2 = xyz2 + (size_t)b * 3 * S_;
  {
    int i = threadIdx.x;   // SPP_ == blockDim.x
    float px = x2[base + i], py = x2[S_ + base + i], pz = x2[2*S_ + base + i];
    pts[i] = make_float4(-2.f*px, -2.f*py, -2.f*pz, px*px + py*py + pz*pz);
  }
  __syncthreads();
  const float* x1 = xyz1 + (size_t)b * 3 * N_;
  float ax = x1[n], ay = x1[N_ + n], az = x1[2*N_ + n];

  float d[2][3]; int id[2][3];
  #pragma unroll
  for (int u = 0; u < 2; u++){
    d[u][0] = d[u][1] = d[u][2] = 1e30f;
    id[u][0] = id[u][1] = id[u][2] = 0;
  }

  for (int s = 0; s < SPP_; s += 8){
    #pragma unroll
    for (int u = 0; u < 8; u++){
      float4 c = pts[s + u];
      float dd = fmaf(ax, c.x, fmaf(ay, c.y, fmaf(az, c.z, c.w)));
      int L = u & 1;
      insert3(d[L][0], d[L][1], d[L][2], id[L][0], id[L][1], id[L][2], dd, base + s + u);
    }
  }
  // merge list 1 into list 0 (exact)
  float e0 = d[0][0], e1 = d[0][1], e2 = d[0][2];
  int   j0 = id[0][0], j1 = id[0][1], j2 = id[0][2];
  #pragma unroll
  for (int j = 0; j < 3; j++)
    insert3(e0, e1, e2, j0, j1, j2, d[1][j], id[1][j]);

  size_t g = (size_t)b * N_ + n;
  partd[(piece*3 + 0)*(size_t)M_ + g] = e0;
  partd[(piece*3 + 1)*(size_t)M_ + g] = e1;
  partd[(piece*3 + 2)*(size_t)M_ + g] = e2;
  parti[(piece*3 + 0)*(size_t)M_ + g] = j0;
  parti[(piece*3 + 1)*(size_t)M_ + g] = j1;
  parti[(piece*3 + 2)*(size_t)M_ + g] = j2;
}

// pass 2: merge 8 pieces' exact top-3 (shifted space), add |x1|^2, weights
__global__ __launch_bounds__(256) void knn_merge_kernel(const float* partd, const int* parti,
                                                        const float* xyz1, int* idx, float* wgt){
  size_t g = (size_t)blockIdx.x * 256 + threadIdx.x;
  float d0 = partd[0*(size_t)M_ + g], d1 = partd[1*(size_t)M_ + g], d2 = partd[2*(size_t)M_ + g];
  int   i0 = parti[0*(size_t)M_ + g], i1 = parti[1*(size_t)M_ + g], i2 = parti[2*(size_t)M_ + g];
  #pragma unroll
  for (int p = 1; p < PIECES_; p++)
    #pragma unroll
    for (int j = 0; j < 3; j++)
      insert3(d0, d1, d2, i0, i1, i2,
              partd[(p*3 + j)*(size_t)M_ + g], parti[(p*3 + j)*(size_t)M_ + g]);

  int b = (int)(g >> 13);
  int n = (int)(g & (N_ - 1));
  const float* x1 = xyz1 + (size_t)b * 3 * N_;
  float ax = x1[n], ay = x1[N_ + n], az = x1[2*N_ + n];
  float x1sq = ax*ax + ay*ay + az*az;

  float e0 = fmaxf(d0 + x1sq, 0.f), e1 = fmaxf(d1 + x1sq, 0.f), e2 = fmaxf(d2 + x1sq, 0.f);
  float r0 = 1.f/(e0 + 1e-8f), r1 = 1.f/(e1 + 1e-8f), r2 = 1.f/(e2 + 1e-8f);
  float rs = 1.f/(r0 + r1 + r2);
  idx[g*3+0] = i0; idx[g*3+1] = i1; idx[g*3+2] = i2;
  wgt[g*3+0] = r0*rs; wgt[g*3+1] = r1*rs; wgt[g*3+2] = r2*rs;
}

// ---------------- gather + weighted interp into x[:,128:384] ----------------
__global__ __launch_bounds__(256) void interp_kernel(const int* idx, const float* wgt,
                                                     const unsigned short* p2t, unsigned short* x){
  int t = threadIdx.x;                 // channel 0..255
  int base = blockIdx.x * 16;
  for (int k = 0; k < 16; k++){
    int g = base + k;
    int b = g >> 13;
    const int*   ip = idx + (size_t)g * 3;
    const float* wp = wgt + (size_t)g * 3;
    const unsigned short* p = p2t + (size_t)b * S_ * C2_;
    float v = wp[0]*bf2f(p[(size_t)ip[0]*C2_ + t])
            + wp[1]*bf2f(p[(size_t)ip[1]*C2_ + t])
            + wp[2]*bf2f(p[(size_t)ip[2]*C2_ + t]);
    x[(size_t)g * IN_ + C1_ + t] = f2bf(v);
  }
}

// ---------------- BN-affine + relu on 8 packed bf16 (for GEMM2 A-staging) ----------------
__device__ __forceinline__ uint4 bn_relu8(uint4 v, const float* a, const float* c, int kb){
  union { uint4 v; unsigned short s[8]; } u; u.v = v;
  #pragma unroll
  for (int j = 0; j < 8; j++){
    float f = bf2f(u.s[j]);
    f = fmaf(a[kb + j], f, c[kb + j]);
    u.s[j] = f2bf(fmaxf(f, 0.f));
  }
  return u.v;
}

// ---------------- MFMA GEMM: C[m,n] = sum_k A[m,k]*W[n,k]; 128x128 tile, BK=32 ------------
__global__ __launch_bounds__(256) void gemm_bt_kernel(const unsigned short* A, const unsigned short* W,
                                                      unsigned short* Cout, int K, int Ntot,
                                                      float* sumv, float* sqv,
                                                      const float* aff_a, const float* aff_c){
  __shared__ unsigned short smA[128*32];  // 8 KB
  __shared__ unsigned short smB[128*32];  // 8 KB
  const int t    = threadIdx.x;
  const int lane = t & 63, wave = t >> 6;
  const int wm   = wave >> 1, wn = wave & 1;
  const size_t m0 = (size_t)blockIdx.x * 128;
  const int    n0 = blockIdx.y * 128;
  const int rowA = t >> 2, ch = t & 3;
  const unsigned short* Ab = A + (m0 + rowA) * (size_t)K + ch*8;
  const unsigned short* Bb = W + (size_t)(n0 + rowA) * K + ch*8;

  const f32x4 fzero = {0.f, 0.f, 0.f, 0.f};
  f32x4 acc[4][4];
  #pragma unroll
  for (int i = 0; i < 4; i++)
    #pragma unroll
    for (int j = 0; j < 4; j++) acc[i][j] = fzero;

  for (int k0 = 0; k0 < K; k0 += 32){
    uint4 va0 = *(const uint4*)(Ab + k0);
    uint4 va1 = *(const uint4*)(Ab + (size_t)64*K + k0);
    uint4 vb0 = *(const uint4*)(Bb + k0);
    uint4 vb1 = *(const uint4*)(Bb + (size_t)64*K + k0);
    if (aff_a){
      int kb = k0 + ch*8;
      va0 = bn_relu8(va0, aff_a, aff_c, kb);
      va1 = bn_relu8(va1, aff_a, aff_c, kb);
    }
    __syncthreads();
    *(uint4*)(&smA[t*8])         = va0;
    *(uint4*)(&smA[(t+256)*8])   = va1;
    *(uint4*)(&smB[t*8])         = vb0;
    *(uint4*)(&smB[(t+256)*8])   = vb1;
    __syncthreads();
    bf16x8 af[4], bfr[4];
    #pragma unroll
    for (int i = 0; i < 4; i++)
      af[i]  = *(const bf16x8*)(&smA[(wm*64 + i*16 + (lane & 15))*32 + (lane >> 4)*8]);
    #pragma unroll
    for (int j = 0; j < 4; j++)
      bfr[j] = *(const bf16x8*)(&smB[(wn*64 + j*16 + (lane & 15))*32 + (lane >> 4)*8]);
    #pragma unroll
    for (int i = 0; i < 4; i++)
      #pragma unroll
      for (int j = 0; j < 4; j++)
        acc[i][j] = __builtin_amdgcn_mfma_f32_16x16x32_bf16(af[i], bfr[j], acc[i][j], 0, 0, 0);
  }

  const int ln = lane & 15, lq = lane >> 4;
  #pragma unroll
  for (int j = 0; j < 4; j++){
    int ncol = n0 + wn*64 + j*16 + ln;
    float s = 0.f, q = 0.f;
    #pragma unroll
    for (int i = 0; i < 4; i++){
      size_t mrow = m0 + wm*64 + i*16 + lq*4;
      #pragma unroll
      for (int r = 0; r < 4; r++){
        float v = acc[i][j][r];
        Cout[(mrow + r) * Ntot + ncol] = f2bf(v);
        s += v; q += v*v;
      }
    }
    s += __shfl_xor(s, 16); s += __shfl_xor(s, 32);
    q += __shfl_xor(q, 16); q += __shfl_xor(q, 32);
    if (lq == 0){
      atomicAdd(&sumv[ncol], s);
      atomicAdd(&sqv[ncol], q);
    }
  }
}

// ---------------- finalize BN: a = g*rsqrt(var+eps), c = be - mean*a ----------------
__global__ void finalize_kernel(const float* sum, const float* sq, const float* g, const float* be,
                                float* a_out, float* c_out, int C){
  int c = threadIdx.x;
  if (c < C){
    float mean = sum[c] * (1.f / M_);
    float var  = sq[c]  * (1.f / M_) - mean*mean;
    float a = g[c] * rsqrtf(var + 1e-5f);
    a_out[c] = a;
    c_out[c] = fmaf(-mean, a, be[c]);
  }
}

// ---------------- final: BN2-affine + relu + transpose to [B,128,N] fp32 ----------------
__global__ __launch_bounds__(256) void out_kernel(const unsigned short* y2, const float* a2,
                                                  const float* c2, float* out){
  __shared__ float lds[64][65];
  int t  = threadIdx.x;
  int b  = blockIdx.z;
  int n0 = blockIdx.y * 64;
  int c0 = blockIdx.x * 64;
  int cc = t & 63, tr = t >> 6;
  float a = a2[c0 + cc], cadd = c2[c0 + cc];
  #pragma unroll
  for (int ph = 0; ph < 16; ph++){
    int nr = tr + ph*4;
    unsigned short v = y2[((size_t)(b*N_ + n0 + nr)) * H2_ + c0 + cc];
    lds[nr][cc] = fmaxf(fmaf(a, bf2f(v), cadd), 0.f);
  }
  __syncthreads();
  #pragma unroll
  for (int ph = 0; ph < 16; ph++){
    int cr = tr + ph*4;
    out[((size_t)(b*H2_ + c0 + cr)) * N_ + n0 + cc] = lds[cc][cr];
  }
}

extern "C" void kernel_launch(void* const* d_in, const int* in_sizes, int n_in,
                              void* d_out, int out_size, void* d_ws, size_t ws_size,
                              hipStream_t stream){
  const float* xyz1 = (const float*)d_in[0];
  const float* xyz2 = (const float*)d_in[1];
  const float* p1   = (const float*)d_in[2];
  const float* p2   = (const float*)d_in[3];
  const float* W1   = (const float*)d_in[4];
  const float* g1   = (const float*)d_in[6];
  const float* be1  = (const float*)d_in[7];
  const float* W2   = (const float*)d_in[8];
  const float* g2   = (const float*)d_in[10];
  const float* be2  = (const float*)d_in[11];
  float* out = (float*)d_out;

  char* ws = (char*)d_ws;
  unsigned short* x    = (unsigned short*)(ws + 0);          // [65536][384] bf16   50.3 MB
  unsigned short* p2t  = (unsigned short*)(ws + 50331648);   // [8][2048][256] bf16  8.4 MB
  unsigned short* y1   = (unsigned short*)(ws + 58720256);   // [65536][256] bf16   33.6 MB
  unsigned short* y2   = (unsigned short*)(ws + 92274688);   // [65536][128] bf16   16.8 MB
  unsigned short* w1b  = (unsigned short*)(ws + 109051904);  // [256][384] bf16
  unsigned short* w2b  = (unsigned short*)(ws + 109248512);  // [128][256] bf16
  int*            idx  = (int*)(ws + 109314048);             // [65536][3] int
  float*          wgt  = (float*)(ws + 110100480);           // [65536][3] f32
  float*          stats= (float*)(ws + 110886912);           // 1536 floats
  float* sum1 = stats;        float* sq1 = stats + 256;
  float* sum2 = stats + 512;  float* sq2 = stats + 640;
  float* a1   = stats + 768;  float* c1  = stats + 1024;
  float* a2   = stats + 1280; float* c2  = stats + 1408;
  // knn partials reuse y1 region (d: 6.3 MB at +0B, i: 6.3 MB at +12.6MB; y1 written later)
  float* partd = (float*)y1;
  int*   parti = (int*)(y1 + 6291456);   // byte offset 12.58 MB into y1 region

  prep_kernel<<<384, 256, 0, stream>>>(W1, W2, w1b, w2b, stats);
  transpose_kernel<<<dim3(64, 8, 8),  256, 0, stream>>>(p2, p2t, 256, 2048, 256, 0);
  transpose_kernel<<<dim3(256, 4, 8), 256, 0, stream>>>(p1, x,   128, 8192, 384, 0);
  knn_kernel<<<dim3(32, 8, PIECES_), 256, 0, stream>>>(xyz1, xyz2, partd, parti);
  knn_merge_kernel<<<256, 256, 0, stream>>>(partd, parti, xyz1, idx, wgt);
  interp_kernel<<<4096, 256, 0, stream>>>(idx, wgt, p2t, x);
  gemm_bt_kernel<<<dim3(512, 2), 256, 0, stream>>>(x,  w1b, y1, 384, 256, sum1, sq1, nullptr, nullptr);
  finalize_kernel<<<1, 256, 0, stream>>>(sum1, sq1, g1, be1, a1, c1, 256);
  gemm_bt_kernel<<<dim3(512, 1), 256, 0, stream>>>(y1, w2b, y2, 256, 128, sum2, sq2, a1, c1);
  finalize_kernel<<<1, 256, 0, stream>>>(sum2, sq2, g2, be2, a2, c2, 128);
  out_kernel<<<dim3(2, 128, 8), 256, 0, stream>>>(y2, a2, c2, out);
}

// Round 6
// 298.814 us; speedup vs baseline: 1.2170x; 1.0677x over previous
//
#include <hip/hip_runtime.h>
#include <stdint.h>

#define B_ 8
#define N_ 8192
#define S_ 2048
#define C1_ 128
#define C2_ 256
#define IN_ 384
#define H1_ 256
#define H2_ 128
#define M_ (B_*N_)   // 65536 rows

typedef short bf16x8 __attribute__((ext_vector_type(8)));
typedef float f32x4 __attribute__((ext_vector_type(4)));

__device__ __forceinline__ float bf2f(unsigned short s){
  union { unsigned int u; float f; } x; x.u = ((unsigned int)s) << 16; return x.f;
}
__device__ __forceinline__ unsigned short f2bf(float f){
  union { float f; unsigned int u; } x; x.f = f;
  unsigned int u = x.u;
  unsigned int r = (u + 0x7FFFu + ((u >> 16) & 1u)) >> 16;
  return (unsigned short)r;
}

// ---------------- prep: convert weights to bf16, zero stats ----------------
__global__ __launch_bounds__(256) void prep_kernel(const float* W1, const float* W2,
                                                   unsigned short* w1b, unsigned short* w2b,
                                                   float* stats){
  int i = blockIdx.x * 256 + threadIdx.x;
  if (i < 256*384) w1b[i] = f2bf(W1[i]);
  if (i < 128*256) w2b[i] = f2bf(W2[i]);
  if (i < 1536)    stats[i] = 0.f;
}

// ---------------- transpose [B][R][L] f32 -> out[b*L + l][stride] bf16 at col_off+r --------
__global__ __launch_bounds__(256) void transpose_kernel(const float* in, unsigned short* out,
                                                        int rows_in, int cols_in,
                                                        int out_stride, int out_col_off){
  __shared__ float tile[32][33];
  int b  = blockIdx.z;
  int l0 = blockIdx.x * 32, r0 = blockIdx.y * 32;
  int tx = threadIdx.x & 31, ty = threadIdx.x >> 5;
  const float* src = in + (size_t)b * rows_in * cols_in;
  #pragma unroll
  for (int rr = ty; rr < 32; rr += 8)
    tile[rr][tx] = src[(size_t)(r0 + rr) * cols_in + l0 + tx];
  __syncthreads();
  unsigned short* dst = out + (size_t)b * cols_in * out_stride;
  #pragma unroll
  for (int rr = ty; rr < 32; rr += 8)
    dst[(size_t)(l0 + rr) * out_stride + out_col_off + r0 + tx] = f2bf(tile[tx][rr]);
}

// ---------------- KNN pass 1: packed-key top-3 per S-piece, exact-recompute tail ----------
// key = (bits(d) & 0xFFFFFF00) | local_idx (8 bits). d >= 0 so positive-float order == uint
// order; 2^-15 relative quantization affects only within-piece near-ties. Winners' exact
// distances are recomputed from LDS before writing partials.
#define PIECES_ 8
#define SPP_ (S_ / PIECES_)   // 256 -> local idx fits 8 bits

__device__ __forceinline__ void insert_k(float& k0, float& k1, float& k2, float x){
  k2 = __builtin_amdgcn_fmed3f(k1, k2, x);
  k1 = __builtin_amdgcn_fmed3f(k0, k1, x);
  k0 = fminf(k0, x);
}

__device__ __forceinline__ void insert3(float& d0, float& d1, float& d2,
                                        int& i0, int& i1, int& i2,
                                        float x, int s){
  bool b0 = x < d0, b1 = x < d1, b2 = x < d2;
  i2 = b1 ? i1 : (b2 ? s : i2);        // index updates read pre-update state
  i1 = b0 ? i0 : (b1 ? s : i1);
  i0 = b0 ? s : i0;
  d2 = __builtin_amdgcn_fmed3f(d1, d2, x);   // uses old d1
  d1 = __builtin_amdgcn_fmed3f(d0, d1, x);   // uses old d0,d1
  d0 = fminf(d0, x);
}

__global__ __launch_bounds__(256, 8) void knn_kernel(const float* xyz1, const float* xyz2,
                                                     float* partd, int* parti){
  __shared__ float4 pts[SPP_];   // 4 KB
  int b = blockIdx.y, piece = blockIdx.z;
  int n = blockIdx.x * 256 + threadIdx.x;
  int base = piece * SPP_;
  const float* x2 = xyz2 + (size_t)b * 3 * S_;
  {
    int i = threadIdx.x;   // SPP_ == blockDim.x
    float px = x2[base + i], py = x2[S_ + base + i], pz = x2[2*S_ + base + i];
    pts[i] = make_float4(-2.f*px, -2.f*py, -2.f*pz, px*px + py*py + pz*pz);
  }
  __syncthreads();
  const float* x1 = xyz1 + (size_t)b * 3 * N_;
  float ax = x1[n], ay = x1[N_ + n], az = x1[2*N_ + n];
  float x1sq = ax*ax + ay*ay + az*az;

  const float KINIT = __uint_as_float(0x7F000000u);   // ~1.7e38, idx bits 0
  float k[2][3];
  k[0][0]=k[0][1]=k[0][2]=KINIT;
  k[1][0]=k[1][1]=k[1][2]=KINIT;

  for (int s = 0; s < SPP_; s += 8){
    #pragma unroll
    for (int u = 0; u < 8; u++){
      float4 c = pts[s + u];
      float dd = fmaf(ax, c.x, fmaf(ay, c.y, fmaf(az, c.z, c.w + x1sq)));
      dd = fmaxf(dd, 0.f);
      float key = __uint_as_float((__float_as_uint(dd) & 0xFFFFFF00u) | (unsigned)(s + u));
      int L = u & 1;
      insert_k(k[L][0], k[L][1], k[L][2], key);
    }
  }
  float e0 = k[0][0], e1 = k[0][1], e2 = k[0][2];
  insert_k(e0, e1, e2, k[1][0]);
  insert_k(e0, e1, e2, k[1][1]);
  insert_k(e0, e1, e2, k[1][2]);

  // decode winners, recompute exact distances from LDS
  float ed[3]; int ei[3];
  float ev[3] = {e0, e1, e2};
  #pragma unroll
  for (int j = 0; j < 3; j++){
    int li = (int)(__float_as_uint(ev[j]) & 0xFFu);
    float4 c = pts[li];
    float dd = fmaf(ax, c.x, fmaf(ay, c.y, fmaf(az, c.z, c.w + x1sq)));
    ed[j] = fmaxf(dd, 0.f);
    ei[j] = base + li;
  }

  size_t g = (size_t)b * N_ + n;
  partd[(piece*3 + 0)*(size_t)M_ + g] = ed[0];
  partd[(piece*3 + 1)*(size_t)M_ + g] = ed[1];
  partd[(piece*3 + 2)*(size_t)M_ + g] = ed[2];
  parti[(piece*3 + 0)*(size_t)M_ + g] = ei[0];
  parti[(piece*3 + 1)*(size_t)M_ + g] = ei[1];
  parti[(piece*3 + 2)*(size_t)M_ + g] = ei[2];
}

// pass 2: exact merge of 8 pieces' top-3 (already true-distance space), weights
__global__ __launch_bounds__(256) void knn_merge_kernel(const float* partd, const int* parti,
                                                        int* idx, float* wgt){
  size_t g = (size_t)blockIdx.x * 256 + threadIdx.x;
  float d0 = partd[0*(size_t)M_ + g], d1 = partd[1*(size_t)M_ + g], d2 = partd[2*(size_t)M_ + g];
  int   i0 = parti[0*(size_t)M_ + g], i1 = parti[1*(size_t)M_ + g], i2 = parti[2*(size_t)M_ + g];
  #pragma unroll
  for (int p = 1; p < PIECES_; p++)
    #pragma unroll
    for (int j = 0; j < 3; j++)
      insert3(d0, d1, d2, i0, i1, i2,
              partd[(p*3 + j)*(size_t)M_ + g], parti[(p*3 + j)*(size_t)M_ + g]);

  float r0 = 1.f/(d0 + 1e-8f), r1 = 1.f/(d1 + 1e-8f), r2 = 1.f/(d2 + 1e-8f);
  float rs = 1.f/(r0 + r1 + r2);
  idx[g*3+0] = i0; idx[g*3+1] = i1; idx[g*3+2] = i2;
  wgt[g*3+0] = r0*rs; wgt[g*3+1] = r1*rs; wgt[g*3+2] = r2*rs;
}

// ---------------- gather + weighted interp into x[:,128:384] ----------------
__global__ __launch_bounds__(256) void interp_kernel(const int* idx, const float* wgt,
                                                     const unsigned short* p2t, unsigned short* x){
  int t = threadIdx.x;                 // channel 0..255
  int base = blockIdx.x * 16;
  for (int k = 0; k < 16; k++){
    int g = base + k;
    int b = g >> 13;
    const int*   ip = idx + (size_t)g * 3;
    const float* wp = wgt + (size_t)g * 3;
    const unsigned short* p = p2t + (size_t)b * S_ * C2_;
    float v = wp[0]*bf2f(p[(size_t)ip[0]*C2_ + t])
            + wp[1]*bf2f(p[(size_t)ip[1]*C2_ + t])
            + wp[2]*bf2f(p[(size_t)ip[2]*C2_ + t]);
    x[(size_t)g * IN_ + C1_ + t] = f2bf(v);
  }
}

// ---------------- BN-affine + relu on 8 packed bf16 (for GEMM2 A-staging) ----------------
__device__ __forceinline__ uint4 bn_relu8(uint4 v, const float* a, const float* c, int kb){
  union { uint4 v; unsigned short s[8]; } u; u.v = v;
  #pragma unroll
  for (int j = 0; j < 8; j++){
    float f = bf2f(u.s[j]);
    f = fmaf(a[kb + j], f, c[kb + j]);
    u.s[j] = f2bf(fmaxf(f, 0.f));
  }
  return u.v;
}

// ---------------- MFMA GEMM: C[m,n] = sum_k A[m,k]*W[n,k]; 128x128 tile, BK=32 ------------
__global__ __launch_bounds__(256) void gemm_bt_kernel(const unsigned short* A, const unsigned short* W,
                                                      unsigned short* Cout, int K, int Ntot,
                                                      float* sumv, float* sqv,
                                                      const float* aff_a, const float* aff_c){
  __shared__ unsigned short smA[128*32];  // 8 KB
  __shared__ unsigned short smB[128*32];  // 8 KB
  const int t    = threadIdx.x;
  const int lane = t & 63, wave = t >> 6;
  const int wm   = wave >> 1, wn = wave & 1;
  const size_t m0 = (size_t)blockIdx.x * 128;
  const int    n0 = blockIdx.y * 128;
  const int rowA = t >> 2, ch = t & 3;
  const unsigned short* Ab = A + (m0 + rowA) * (size_t)K + ch*8;
  const unsigned short* Bb = W + (size_t)(n0 + rowA) * K + ch*8;

  const f32x4 fzero = {0.f, 0.f, 0.f, 0.f};
  f32x4 acc[4][4];
  #pragma unroll
  for (int i = 0; i < 4; i++)
    #pragma unroll
    for (int j = 0; j < 4; j++) acc[i][j] = fzero;

  for (int k0 = 0; k0 < K; k0 += 32){
    uint4 va0 = *(const uint4*)(Ab + k0);
    uint4 va1 = *(const uint4*)(Ab + (size_t)64*K + k0);
    uint4 vb0 = *(const uint4*)(Bb + k0);
    uint4 vb1 = *(const uint4*)(Bb + (size_t)64*K + k0);
    if (aff_a){
      int kb = k0 + ch*8;
      va0 = bn_relu8(va0, aff_a, aff_c, kb);
      va1 = bn_relu8(va1, aff_a, aff_c, kb);
    }
    __syncthreads();
    *(uint4*)(&smA[t*8])         = va0;
    *(uint4*)(&smA[(t+256)*8])   = va1;
    *(uint4*)(&smB[t*8])         = vb0;
    *(uint4*)(&smB[(t+256)*8])   = vb1;
    __syncthreads();
    bf16x8 af[4], bfr[4];
    #pragma unroll
    for (int i = 0; i < 4; i++)
      af[i]  = *(const bf16x8*)(&smA[(wm*64 + i*16 + (lane & 15))*32 + (lane >> 4)*8]);
    #pragma unroll
    for (int j = 0; j < 4; j++)
      bfr[j] = *(const bf16x8*)(&smB[(wn*64 + j*16 + (lane & 15))*32 + (lane >> 4)*8]);
    #pragma unroll
    for (int i = 0; i < 4; i++)
      #pragma unroll
      for (int j = 0; j < 4; j++)
        acc[i][j] = __builtin_amdgcn_mfma_f32_16x16x32_bf16(af[i], bfr[j], acc[i][j], 0, 0, 0);
  }

  const int ln = lane & 15, lq = lane >> 4;
  #pragma unroll
  for (int j = 0; j < 4; j++){
    int ncol = n0 + wn*64 + j*16 + ln;
    float s = 0.f, q = 0.f;
    #pragma unroll
    for (int i = 0; i < 4; i++){
      size_t mrow = m0 + wm*64 + i*16 + lq*4;
      #pragma unroll
      for (int r = 0; r < 4; r++){
        float v = acc[i][j][r];
        Cout[(mrow + r) * Ntot + ncol] = f2bf(v);
        s += v; q += v*v;
      }
    }
    s += __shfl_xor(s, 16); s += __shfl_xor(s, 32);
    q += __shfl_xor(q, 16); q += __shfl_xor(q, 32);
    if (lq == 0){
      atomicAdd(&sumv[ncol], s);
      atomicAdd(&sqv[ncol], q);
    }
  }
}

// ---------------- finalize BN: a = g*rsqrt(var+eps), c = be - mean*a ----------------
__global__ void finalize_kernel(const float* sum, const float* sq, const float* g, const float* be,
                                float* a_out, float* c_out, int C){
  int c = threadIdx.x;
  if (c < C){
    float mean = sum[c] * (1.f / M_);
    float var  = sq[c]  * (1.f / M_) - mean*mean;
    float a = g[c] * rsqrtf(var + 1e-5f);
    a_out[c] = a;
    c_out[c] = fmaf(-mean, a, be[c]);
  }
}

// ---------------- final: BN2-affine + relu + transpose to [B,128,N] fp32 ----------------
__global__ __launch_bounds__(256) void out_kernel(const unsigned short* y2, const float* a2,
                                                  const float* c2, float* out){
  __shared__ float lds[64][65];
  int t  = threadIdx.x;
  int b  = blockIdx.z;
  int n0 = blockIdx.y * 64;
  int c0 = blockIdx.x * 64;
  int cc = t & 63, tr = t >> 6;
  float a = a2[c0 + cc], cadd = c2[c0 + cc];
  #pragma unroll
  for (int ph = 0; ph < 16; ph++){
    int nr = tr + ph*4;
    unsigned short v = y2[((size_t)(b*N_ + n0 + nr)) * H2_ + c0 + cc];
    lds[nr][cc] = fmaxf(fmaf(a, bf2f(v), cadd), 0.f);
  }
  __syncthreads();
  #pragma unroll
  for (int ph = 0; ph < 16; ph++){
    int cr = tr + ph*4;
    out[((size_t)(b*H2_ + c0 + cr)) * N_ + n0 + cc] = lds[cc][cr];
  }
}

extern "C" void kernel_launch(void* const* d_in, const int* in_sizes, int n_in,
                              void* d_out, int out_size, void* d_ws, size_t ws_size,
                              hipStream_t stream){
  const float* xyz1 = (const float*)d_in[0];
  const float* xyz2 = (const float*)d_in[1];
  const float* p1   = (const float*)d_in[2];
  const float* p2   = (const float*)d_in[3];
  const float* W1   = (const float*)d_in[4];
  const float* g1   = (const float*)d_in[6];
  const float* be1  = (const float*)d_in[7];
  const float* W2   = (const float*)d_in[8];
  const float* g2   = (const float*)d_in[10];
  const float* be2  = (const float*)d_in[11];
  float* out = (float*)d_out;

  char* ws = (char*)d_ws;
  unsigned short* x    = (unsigned short*)(ws + 0);          // [65536][384] bf16   50.3 MB
  unsigned short* p2t  = (unsigned short*)(ws + 50331648);   // [8][2048][256] bf16  8.4 MB
  unsigned short* y1   = (unsigned short*)(ws + 58720256);   // [65536][256] bf16   33.6 MB
  unsigned short* y2   = (unsigned short*)(ws + 92274688);   // [65536][128] bf16   16.8 MB
  unsigned short* w1b  = (unsigned short*)(ws + 109051904);  // [256][384] bf16
  unsigned short* w2b  = (unsigned short*)(ws + 109248512);  // [128][256] bf16
  int*            idx  = (int*)(ws + 109314048);             // [65536][3] int
  float*          wgt  = (float*)(ws + 110100480);           // [65536][3] f32
  float*          stats= (float*)(ws + 110886912);           // 1536 floats
  float* sum1 = stats;        float* sq1 = stats + 256;
  float* sum2 = stats + 512;  float* sq2 = stats + 640;
  float* a1   = stats + 768;  float* c1  = stats + 1024;
  float* a2   = stats + 1280; float* c2  = stats + 1408;
  // knn partials reuse y1 region (d: 6.3 MB at +0B, i: 6.3 MB at +12.6MB; y1 written later)
  float* partd = (float*)y1;
  int*   parti = (int*)(y1 + 6291456);   // byte offset 12.58 MB into y1 region

  prep_kernel<<<384, 256, 0, stream>>>(W1, W2, w1b, w2b, stats);
  transpose_kernel<<<dim3(64, 8, 8),  256, 0, stream>>>(p2, p2t, 256, 2048, 256, 0);
  transpose_kernel<<<dim3(256, 4, 8), 256, 0, stream>>>(p1, x,   128, 8192, 384, 0);
  knn_kernel<<<dim3(32, 8, PIECES_), 256, 0, stream>>>(xyz1, xyz2, partd, parti);
  knn_merge_kernel<<<256, 256, 0, stream>>>(partd, parti, idx, wgt);
  interp_kernel<<<4096, 256, 0, stream>>>(idx, wgt, p2t, x);
  gemm_bt_kernel<<<dim3(512, 2), 256, 0, stream>>>(x,  w1b, y1, 384, 256, sum1, sq1, nullptr, nullptr);
  finalize_kernel<<<1, 256, 0, stream>>>(sum1, sq1, g1, be1, a1, c1, 256);
  gemm_bt_kernel<<<dim3(512, 1), 256, 0, stream>>>(y1, w2b, y2, 256, 128, sum2, sq2, a1, c1);
  finalize_kernel<<<1, 256, 0, stream>>>(sum2, sq2, g2, be2, a2, c2, 128);
  out_kernel<<<dim3(2, 128, 8), 256, 0, stream>>>(y2, a2, c2, out);
}